// Round 7
// baseline (184.507 us; speedup 1.0000x reference)
//
#include <hip/hip_runtime.h>
#include <hip/hip_bf16.h>
#include <stdint.h>

typedef short bf16x8 __attribute__((ext_vector_type(8)));
typedef float f32x4 __attribute__((ext_vector_type(4)));
typedef unsigned short u16x4 __attribute__((ext_vector_type(4)));
typedef unsigned short u16x8 __attribute__((ext_vector_type(8)));

#define GLOAD16(g, l) __builtin_amdgcn_global_load_lds( \
    (const __attribute__((address_space(1))) void*)(g), \
    (__attribute__((address_space(3))) void*)(l), 16, 0, 0)

__device__ __forceinline__ unsigned short f2bf(float f) {
  unsigned u = __float_as_uint(f);
  unsigned r = (u + 0x7fffu + ((u >> 16) & 1u)) >> 16;
  return (unsigned short)r;
}

// ---------------- prep (+norm merged): Wt[f][k2'] bf16 (k2' = e*32+c);
// wfragG = projection weights in MFMA B-frag order; nrm[b][d] = mask^T mask.
__global__ __launch_bounds__(256) void prep_norm_k(
    const float* __restrict__ lw, const float* __restrict__ rw,
    const float* __restrict__ ow, const float* __restrict__ mask,
    unsigned short* __restrict__ Wt, unsigned short* __restrict__ wfragG,
    float* __restrict__ nrm) {
  const int bid = blockIdx.x;
  if (bid < 512) {
    int idx = bid * 256 + threadIdx.x;
    if (idx < 131072) {
      int f = idx >> 10, k2 = idx & 1023;
      int e = k2 >> 5, c = k2 & 31;
      Wt[idx] = f2bf(ow[(size_t)((c << 5) + e) * 128 + f]);
    }
    if (idx < 16384) {
      int frag = idx >> 9, lane = (idx >> 3) & 63, j = idx & 7;
      int wc = frag >> 4, ni = (frag >> 3) & 1, kk = frag & 7;
      int mrow = lane & 15, g = lane >> 4;
      int c = wc * 32 + ni * 16 + mrow;
      int k = kk * 32 + g * 8 + j;
      wfragG[idx] = f2bf(c < 32 ? lw[k * 32 + c] : rw[k * 32 + (c - 32)]);
    }
  } else {
    const int b = bid - 512, d = threadIdx.x;
    float s = 0.f;
    #pragma unroll 8
    for (int a = 0; a < 512; ++a)
      s += mask[a * 256 + b] * mask[a * 256 + d];
    nrm[(b << 8) + d] = s;
  }
}

// ---------------- fused LayerNorm + projections via MFMA (unchanged from R5)
__global__ __launch_bounds__(256, 4) void ln_proj(
    const float* __restrict__ act, const float* __restrict__ mask,
    const float* __restrict__ lns, const float* __restrict__ lno,
    const float* __restrict__ lb, const float* __restrict__ rb,
    const unsigned short* __restrict__ wfragG,
    unsigned short* __restrict__ Lt, unsigned short* __restrict__ Rt) {
  __shared__ char smem[32768];  // A tile [64 rows][512B swz]; reused as [64c][64a]
  const int tid = threadIdx.x;
  const int lane = tid & 63;
  const int w = tid >> 6;
  const int b = blockIdx.y;
  const int a0 = blockIdx.x << 6;
  const int l = tid & 15;
  const int rg = tid >> 4;

  f32x4 sc[4], of[4];
  #pragma unroll
  for (int j = 0; j < 4; ++j) {
    sc[j] = *(const f32x4*)(lns + (l << 4) + (j << 2));
    of[j] = *(const f32x4*)(lno + (l << 4) + (j << 2));
  }

  #pragma unroll
  for (int i = 0; i < 4; ++i) {
    const int r = rg + (i << 4);
    const float* src = act + ((size_t)(a0 + r) * 256 + b) * 256 + (l << 4);
    f32x4 xv[4];
    #pragma unroll
    for (int j = 0; j < 4; ++j) xv[j] = *(const f32x4*)(src + (j << 2));
    float s = 0.f, sq = 0.f;
    #pragma unroll
    for (int j = 0; j < 4; ++j) {
      f32x4 v = xv[j];
      s += v[0] + v[1] + v[2] + v[3];
      sq += v[0] * v[0] + v[1] * v[1] + v[2] * v[2] + v[3] * v[3];
    }
    s += __shfl_xor(s, 1); sq += __shfl_xor(sq, 1);
    s += __shfl_xor(s, 2); sq += __shfl_xor(sq, 2);
    s += __shfl_xor(s, 4); sq += __shfl_xor(sq, 4);
    s += __shfl_xor(s, 8); sq += __shfl_xor(sq, 8);
    const float mu = s * (1.f / 256.f);
    const float rs = rsqrtf(sq * (1.f / 256.f) - mu * mu + 1e-5f);
    #pragma unroll
    for (int hh = 0; hh < 2; ++hh) {
      u16x8 pk;
      #pragma unroll
      for (int j2 = 0; j2 < 2; ++j2) {
        const int j = (hh << 1) + j2;
        #pragma unroll
        for (int e = 0; e < 4; ++e)
          pk[(j2 << 2) + e] = f2bf((xv[j][e] - mu) * rs * sc[j][e] + of[j][e]);
      }
      const int c = (l << 1) + hh;
      *(u16x8*)(smem + (r << 9) + ((c ^ (r & 7)) << 4)) = pk;
    }
  }
  __syncthreads();

  const int wr = w >> 1, wc = w & 1;
  const int mrow = lane & 15, g = lane >> 4;
  f32x4 acc[2][2];
  #pragma unroll
  for (int i = 0; i < 2; ++i)
    #pragma unroll
    for (int jj = 0; jj < 2; ++jj) acc[i][jj] = (f32x4){0.f, 0.f, 0.f, 0.f};
  #pragma unroll
  for (int kk = 0; kk < 8; ++kk) {
    bf16x8 af[2], bfr[2];
    #pragma unroll
    for (int mi = 0; mi < 2; ++mi) {
      const int row = (wr << 5) + (mi << 4) + mrow;
      af[mi] = *(const bf16x8*)(smem + (row << 9) + ((((kk << 2) + g) ^ (row & 7)) << 4));
    }
    #pragma unroll
    for (int ni = 0; ni < 2; ++ni)
      bfr[ni] = *(const bf16x8*)(wfragG + (size_t)((((wc << 1) + ni) << 3) + kk) * 512 + (lane << 3));
    #pragma unroll
    for (int mi = 0; mi < 2; ++mi)
      #pragma unroll
      for (int ni = 0; ni < 2; ++ni)
        acc[mi][ni] = __builtin_amdgcn_mfma_f32_16x16x32_bf16(af[mi], bfr[ni], acc[mi][ni], 0, 0, 0);
  }
  __syncthreads();

  #pragma unroll
  for (int ni = 0; ni < 2; ++ni) {
    const int c = (wc << 5) + (ni << 4) + mrow;
    const float bias = (wc == 0) ? lb[(ni << 4) + mrow] : rb[(ni << 4) + mrow];
    #pragma unroll
    for (int mi = 0; mi < 2; ++mi) {
      const int aB = (wr << 5) + (mi << 4) + (g << 2);
      u16x4 pk;
      #pragma unroll
      for (int qq = 0; qq < 4; ++qq) {
        const float mk = mask[(size_t)(a0 + aB + qq) * 256 + b];
        pk[qq] = f2bf((acc[mi][ni][qq] + bias) * mk);
      }
      *(u16x4*)(smem + (c << 7) + ((((aB >> 3) & 7) ^ (c & 7)) << 4) + ((aB & 7) << 1)) = pk;
    }
  }
  __syncthreads();

  #pragma unroll
  for (int s = 0; s < 2; ++s) {
    const int c = (w << 4) + (s << 3) + (lane >> 3);
    const int gr = lane & 7;
    const u16x8 v = *(const u16x8*)(smem + (c << 7) + ((gr ^ (c & 7)) << 4));
    unsigned short* dst = (c < 32) ? Lt : Rt;
    *(u16x8*)(dst + (size_t)(b * 32 + (c & 31)) * 512 + a0 + (gr << 3)) = v;
  }
}

// ---------------- main GEMM: 256m x 128n tile, 8 waves (4wr x 2wn, 64x64 each),
// BK=32, 16x16x32 MFMA, TRIPLE-buffered LDS (3 x 24KB) -> 2 blocks/CU.
// One barrier per K-tile: {8 ds_reads; stage t+2 (3 gload) into buf(t+2)%3;
// lgkmcnt(0); 16 MFMA; vmcnt(3); bar}. Never vmcnt(0) until tail.
// Fused epilogue: op tile -> opvec[32][2048B] bf16 (LDS reuse) -> x Wt -> out.
__global__ __launch_bounds__(512, 4) void gemm_fused(
    const unsigned short* __restrict__ Lt, const unsigned short* __restrict__ Rt,
    const unsigned short* __restrict__ Wt, const float* __restrict__ nrm,
    const float* __restrict__ outb, float* __restrict__ out) {
  __shared__ char smem[73728];  // 3 x (A 16KB | B 8KB); epilogue opvec 64KB
  const int tid = threadIdx.x;
  const int lane = tid & 63;
  const int w = tid >> 6;
  const int wr = w >> 1, wn = w & 1;   // wave owns 64m x 64n
  const int mrow = lane & 15, g = lane >> 4;

  // XCD map: xcd owns nb-stripe [xcd*8, xcd*8+8); walk 8mb x 8nb octets
  const int bid = blockIdx.x;
  const int xcd = bid & 7, j = bid >> 3;
  const int sub = j & 63;
  const int mb = ((j >> 6) << 3) + (sub >> 3);  // 0..31
  const int nb = (xcd << 3) + (sub & 7);        // 0..63
  const int m0i = mb << 8, n0i = nb << 7;

  const int srow = tid >> 2;                       // 0..127
  const int scol = (((tid & 3) ^ (srow & 3)) << 3);  // pre-swz source col (elems)

  f32x4 acc[4][4];
  #pragma unroll
  for (int i = 0; i < 4; ++i)
    #pragma unroll
    for (int jj = 0; jj < 4; ++jj) acc[i][jj] = (f32x4){0.f, 0.f, 0.f, 0.f};

  auto STGA = [&](int buf, int half, int kt) {
    GLOAD16(Lt + ((size_t)(m0i + (half << 7) + srow) << 9) + (kt << 5) + scol,
            smem + buf + (half << 13) + (tid << 4));
  };
  auto STGB = [&](int buf, int kt) {
    GLOAD16(Rt + ((size_t)(n0i + srow) << 9) + (kt << 5) + scol,
            smem + buf + 16384 + (tid << 4));
  };

  // prologue: tiles 0 (buf0) and 1 (buf1)
  STGA(0, 0, 0); STGA(0, 1, 0); STGB(0, 0);
  STGA(24576, 0, 1); STGA(24576, 1, 1); STGB(24576, 1);
  asm volatile("s_waitcnt vmcnt(3)" ::: "memory");  // tile 0 landed
  __builtin_amdgcn_s_barrier();

  int cur = 0;
  #pragma unroll 1
  for (int t = 0; t < 16; ++t) {
    const char* bufp = smem + cur * 24576;
    bf16x8 af[4], bfv[4];
    #pragma unroll
    for (int mi = 0; mi < 4; ++mi) {
      const int row = (wr << 6) + (mi << 4) + mrow;
      af[mi] = *(const bf16x8*)(bufp + (row << 6) + ((g ^ (row & 3)) << 4));
    }
    #pragma unroll
    for (int ni = 0; ni < 4; ++ni) {
      const int row = (wn << 6) + (ni << 4) + mrow;
      bfv[ni] = *(const bf16x8*)(bufp + 16384 + (row << 6) + ((g ^ (row & 3)) << 4));
    }
    if (t < 14) {  // stage t+2 into buf (cur+2)%3 = (cur-1)%3
      const int sb = (cur == 0) ? 49152 : (cur == 1) ? 0 : 24576;
      STGA(sb, 0, t + 2); STGA(sb, 1, t + 2); STGB(sb, t + 2);
    }
    asm volatile("s_waitcnt lgkmcnt(0)" ::: "memory");
    __builtin_amdgcn_sched_barrier(0);
    __builtin_amdgcn_s_setprio(1);
    #pragma unroll
    for (int mi = 0; mi < 4; ++mi)
      #pragma unroll
      for (int ni = 0; ni < 4; ++ni)
        acc[mi][ni] = __builtin_amdgcn_mfma_f32_16x16x32_bf16(
            af[mi], bfv[ni], acc[mi][ni], 0, 0, 0);
    __builtin_amdgcn_s_setprio(0);
    if (t < 14)       asm volatile("s_waitcnt vmcnt(3)" ::: "memory");
    else if (t == 14) asm volatile("s_waitcnt vmcnt(0)" ::: "memory");
    __builtin_amdgcn_s_barrier();
    cur = (cur == 2) ? 0 : cur + 1;
  }
  __syncthreads();

  // scatter op tile -> opvec[p][k2'] bf16 (p = bloc*4+dloc, k2' = e*32+c, dual-XOR)
  // m = wr*64+mi*16+g*4+qq; n = wn*64+ni*16+mrow; p = (m>>5)*4+(n>>5)
  #pragma unroll
  for (int mi = 0; mi < 4; ++mi) {
    #pragma unroll
    for (int ni = 0; ni < 4; ++ni) {
      const int p = (((wr << 1) + (mi >> 1)) << 2) + (wn << 1) + (ni >> 1);
      const int ow_ = ((ni & 1) << 10) + (mrow << 6) + ((mi & 1) << 5) + (g << 3);
      u16x4 pk;
      #pragma unroll
      for (int qq = 0; qq < 4; ++qq) pk[qq] = f2bf(acc[mi][ni][qq]);
      *(u16x4*)(smem + (p << 11) + (ow_ ^ ((p & 7) << 4) ^ (((ow_ >> 7) & 7) << 4))) = pk;
    }
  }
  __syncthreads();

  // prefetch nrm + rcp (hidden under stage2)
  f32x4 invn[2];
  #pragma unroll
  for (int pg = 0; pg < 2; ++pg) {
    const int bb = (mb << 3) + (pg << 2) + g;
    const f32x4 nv = *(const f32x4*)(nrm + (bb << 8) + (nb << 2));
    #pragma unroll
    for (int qq = 0; qq < 4; ++qq) invn[pg][qq] = __builtin_amdgcn_rcpf(1e-3f + nv[qq]);
  }

  // stage 2: out2[p][f] = sum_k2' opvec[p][k2'] * Wt[f][k2']; wave owns 16 f x 32 p
  const int f0 = w << 4;
  f32x4 acc2[2];
  acc2[0] = (f32x4){0.f, 0.f, 0.f, 0.f};
  acc2[1] = (f32x4){0.f, 0.f, 0.f, 0.f};
  const unsigned short* wrow = Wt + (size_t)(f0 + mrow) * 1024;
  #pragma unroll 8
  for (int kk2 = 0; kk2 < 32; ++kk2) {
    const bf16x8 b2 = *(const bf16x8*)(wrow + (kk2 << 5) + (g << 3));
    const int orr = (kk2 << 6) + (g << 4);
    #pragma unroll
    for (int pg = 0; pg < 2; ++pg) {
      const int prow = (pg << 4) + mrow;
      const bf16x8 a2 = *(const bf16x8*)(smem + (prow << 11) +
          (orr ^ ((prow & 7) << 4) ^ (((orr >> 7) & 7) << 4)));
      acc2[pg] = __builtin_amdgcn_mfma_f32_16x16x32_bf16(a2, b2, acc2[pg], 0, 0, 0);
    }
  }

  // epilogue: bias, * (1/(eps+norm)), store
  const float ob_ = outb[f0 + mrow];
  #pragma unroll
  for (int pg = 0; pg < 2; ++pg) {
    #pragma unroll
    for (int qq = 0; qq < 4; ++qq) {
      const int p = (pg << 4) + (g << 2) + qq;
      const int bb = (mb << 3) + (p >> 2);
      const int dd = (nb << 2) + (p & 3);
      out[(size_t)((bb << 8) + dd) * 128 + f0 + mrow] = (acc2[pg][qq] + ob_) * invn[pg][qq];
    }
  }
}

extern "C" void kernel_launch(void* const* d_in, const int* in_sizes, int n_in,
                              void* d_out, int out_size, void* d_ws, size_t ws_size,
                              hipStream_t stream) {
  const float* act = (const float*)d_in[0];
  const float* mask = (const float*)d_in[1];
  const float* lns = (const float*)d_in[2];
  const float* lno = (const float*)d_in[3];
  const float* lw = (const float*)d_in[4];
  const float* lb = (const float*)d_in[5];
  const float* rw = (const float*)d_in[6];
  const float* rbv = (const float*)d_in[7];
  const float* ow = (const float*)d_in[8];
  const float* ob = (const float*)d_in[9];
  float* out = (float*)d_out;
  char* ws = (char*)d_ws;

  unsigned short* Lt = (unsigned short*)(ws);               // 8 MB
  unsigned short* Rt = (unsigned short*)(ws + 8388608);     // 8 MB
  unsigned short* Wt = (unsigned short*)(ws + 16777216);    // 256 KB
  unsigned short* wfragG = (unsigned short*)(ws + 17039360);// 32 KB
  float* nrm = (float*)(ws + 17072128);                     // 256 KB

  hipLaunchKernelGGL(prep_norm_k, dim3(768), dim3(256), 0, stream,
                     lw, rw, ow, mask, Wt, wfragG, nrm);
  hipLaunchKernelGGL(ln_proj, dim3(8, 256), dim3(256), 0, stream,
                     act, mask, lns, lno, lb, rbv, wfragG, Lt, Rt);
  hipLaunchKernelGGL(gemm_fused, dim3(2048), dim3(512), 0, stream,
                     Lt, Rt, Wt, nrm, ob, out);
}

// Round 8
// 151.291 us; speedup vs baseline: 1.2196x; 1.2196x over previous
//
#include <hip/hip_runtime.h>
#include <hip/hip_bf16.h>
#include <stdint.h>

typedef short bf16x8 __attribute__((ext_vector_type(8)));
typedef float f32x4 __attribute__((ext_vector_type(4)));
typedef unsigned short u16x4 __attribute__((ext_vector_type(4)));
typedef unsigned short u16x8 __attribute__((ext_vector_type(8)));

#define GLOAD16(g, l) __builtin_amdgcn_global_load_lds( \
    (const __attribute__((address_space(1))) void*)(g), \
    (__attribute__((address_space(3))) void*)(l), 16, 0, 0)

__device__ __forceinline__ unsigned short f2bf(float f) {
  unsigned u = __float_as_uint(f);
  unsigned r = (u + 0x7fffu + ((u >> 16) & 1u)) >> 16;
  return (unsigned short)r;
}

// ---------------- prep (+norm merged): Wt[f][k2'] bf16 (k2' = e*32+c);
// wfragG = projection weights in MFMA B-frag order; nrm[b][d] = mask^T mask.
__global__ __launch_bounds__(256) void prep_norm_k(
    const float* __restrict__ lw, const float* __restrict__ rw,
    const float* __restrict__ ow, const float* __restrict__ mask,
    unsigned short* __restrict__ Wt, unsigned short* __restrict__ wfragG,
    float* __restrict__ nrm) {
  const int bid = blockIdx.x;
  if (bid < 512) {
    int idx = bid * 256 + threadIdx.x;
    if (idx < 131072) {
      int f = idx >> 10, k2 = idx & 1023;
      int e = k2 >> 5, c = k2 & 31;
      Wt[idx] = f2bf(ow[(size_t)((c << 5) + e) * 128 + f]);
    }
    if (idx < 16384) {
      int frag = idx >> 9, lane = (idx >> 3) & 63, j = idx & 7;
      int wc = frag >> 4, ni = (frag >> 3) & 1, kk = frag & 7;
      int mrow = lane & 15, g = lane >> 4;
      int c = wc * 32 + ni * 16 + mrow;
      int k = kk * 32 + g * 8 + j;
      wfragG[idx] = f2bf(c < 32 ? lw[k * 32 + c] : rw[k * 32 + (c - 32)]);
    }
  } else {
    const int b = bid - 512, d = threadIdx.x;
    float s = 0.f;
    #pragma unroll 8
    for (int a = 0; a < 512; ++a)
      s += mask[a * 256 + b] * mask[a * 256 + d];
    nrm[(b << 8) + d] = s;
  }
}

// ---------------- fused LayerNorm + projections via MFMA (unchanged from R5)
__global__ __launch_bounds__(256, 4) void ln_proj(
    const float* __restrict__ act, const float* __restrict__ mask,
    const float* __restrict__ lns, const float* __restrict__ lno,
    const float* __restrict__ lb, const float* __restrict__ rb,
    const unsigned short* __restrict__ wfragG,
    unsigned short* __restrict__ Lt, unsigned short* __restrict__ Rt) {
  __shared__ char smem[32768];  // A tile [64 rows][512B swz]; reused as [64c][64a]
  const int tid = threadIdx.x;
  const int lane = tid & 63;
  const int w = tid >> 6;
  const int b = blockIdx.y;
  const int a0 = blockIdx.x << 6;
  const int l = tid & 15;
  const int rg = tid >> 4;

  f32x4 sc[4], of[4];
  #pragma unroll
  for (int j = 0; j < 4; ++j) {
    sc[j] = *(const f32x4*)(lns + (l << 4) + (j << 2));
    of[j] = *(const f32x4*)(lno + (l << 4) + (j << 2));
  }

  #pragma unroll
  for (int i = 0; i < 4; ++i) {
    const int r = rg + (i << 4);
    const float* src = act + ((size_t)(a0 + r) * 256 + b) * 256 + (l << 4);
    f32x4 xv[4];
    #pragma unroll
    for (int j = 0; j < 4; ++j) xv[j] = *(const f32x4*)(src + (j << 2));
    float s = 0.f, sq = 0.f;
    #pragma unroll
    for (int j = 0; j < 4; ++j) {
      f32x4 v = xv[j];
      s += v[0] + v[1] + v[2] + v[3];
      sq += v[0] * v[0] + v[1] * v[1] + v[2] * v[2] + v[3] * v[3];
    }
    s += __shfl_xor(s, 1); sq += __shfl_xor(sq, 1);
    s += __shfl_xor(s, 2); sq += __shfl_xor(sq, 2);
    s += __shfl_xor(s, 4); sq += __shfl_xor(sq, 4);
    s += __shfl_xor(s, 8); sq += __shfl_xor(sq, 8);
    const float mu = s * (1.f / 256.f);
    const float rs = rsqrtf(sq * (1.f / 256.f) - mu * mu + 1e-5f);
    #pragma unroll
    for (int hh = 0; hh < 2; ++hh) {
      u16x8 pk;
      #pragma unroll
      for (int j2 = 0; j2 < 2; ++j2) {
        const int j = (hh << 1) + j2;
        #pragma unroll
        for (int e = 0; e < 4; ++e)
          pk[(j2 << 2) + e] = f2bf((xv[j][e] - mu) * rs * sc[j][e] + of[j][e]);
      }
      const int c = (l << 1) + hh;
      *(u16x8*)(smem + (r << 9) + ((c ^ (r & 7)) << 4)) = pk;
    }
  }
  __syncthreads();

  const int wr = w >> 1, wc = w & 1;
  const int mrow = lane & 15, g = lane >> 4;
  f32x4 acc[2][2];
  #pragma unroll
  for (int i = 0; i < 2; ++i)
    #pragma unroll
    for (int jj = 0; jj < 2; ++jj) acc[i][jj] = (f32x4){0.f, 0.f, 0.f, 0.f};
  #pragma unroll
  for (int kk = 0; kk < 8; ++kk) {
    bf16x8 af[2], bfr[2];
    #pragma unroll
    for (int mi = 0; mi < 2; ++mi) {
      const int row = (wr << 5) + (mi << 4) + mrow;
      af[mi] = *(const bf16x8*)(smem + (row << 9) + ((((kk << 2) + g) ^ (row & 7)) << 4));
    }
    #pragma unroll
    for (int ni = 0; ni < 2; ++ni)
      bfr[ni] = *(const bf16x8*)(wfragG + (size_t)((((wc << 1) + ni) << 3) + kk) * 512 + (lane << 3));
    #pragma unroll
    for (int mi = 0; mi < 2; ++mi)
      #pragma unroll
      for (int ni = 0; ni < 2; ++ni)
        acc[mi][ni] = __builtin_amdgcn_mfma_f32_16x16x32_bf16(af[mi], bfr[ni], acc[mi][ni], 0, 0, 0);
  }
  __syncthreads();

  #pragma unroll
  for (int ni = 0; ni < 2; ++ni) {
    const int c = (wc << 5) + (ni << 4) + mrow;
    const float bias = (wc == 0) ? lb[(ni << 4) + mrow] : rb[(ni << 4) + mrow];
    #pragma unroll
    for (int mi = 0; mi < 2; ++mi) {
      const int aB = (wr << 5) + (mi << 4) + (g << 2);
      u16x4 pk;
      #pragma unroll
      for (int qq = 0; qq < 4; ++qq) {
        const float mk = mask[(size_t)(a0 + aB + qq) * 256 + b];
        pk[qq] = f2bf((acc[mi][ni][qq] + bias) * mk);
      }
      *(u16x4*)(smem + (c << 7) + ((((aB >> 3) & 7) ^ (c & 7)) << 4) + ((aB & 7) << 1)) = pk;
    }
  }
  __syncthreads();

  #pragma unroll
  for (int s = 0; s < 2; ++s) {
    const int c = (w << 4) + (s << 3) + (lane >> 3);
    const int gr = lane & 7;
    const u16x8 v = *(const u16x8*)(smem + (c << 7) + ((gr ^ (c & 7)) << 4));
    unsigned short* dst = (c < 32) ? Lt : Rt;
    *(u16x8*)(dst + (size_t)(b * 32 + (c & 31)) * 512 + a0 + (gr << 3)) = v;
  }
}

// ---------------- main GEMM: 256x256 tile, 8 waves, BK=64, 16x16x32 MFMA.
// 2 barriers/K-tile; K-tile body (24 ds_read_b128 + 64 MFMA) is left to the
// COMPILER to schedule (fine-grained lgkmcnt interleave — no asm pins).
// {kk-loop; bar; STGALL(t+2 -> cbuf); vmcnt(8); bar}. 2-tile-deep prefetch
// with 2 buffers; never vmcnt(0) in steady state.
// Fused epilogue: op tile -> opvec[64][1024] bf16 (LDS reuse) -> x Wt -> out.
__global__ __launch_bounds__(512, 2) void gemm_fused(
    const unsigned short* __restrict__ Lt, const unsigned short* __restrict__ Rt,
    const unsigned short* __restrict__ Wt, const float* __restrict__ nrm,
    const float* __restrict__ outb, float* __restrict__ out) {
  __shared__ char smem[131072];  // 2 bufs x (A 32KB | B 32KB); reused as opvec
  const int tid = threadIdx.x;
  const int lane = tid & 63;
  const int w = tid >> 6;
  const int wr = w >> 2, wc = w & 3;   // wave owns 128m x 64n
  const int mrow = lane & 15, g = lane >> 4;

  // XCD mapping with L2-octet order (8mb x 4nb per XCD)
  const int bid = blockIdx.x;
  const int xcd = bid & 7, jj_ = bid >> 3;
  const int mb = ((jj_ >> 5) << 3) | (jj_ & 7);
  const int nb = (xcd << 2) | ((jj_ >> 3) & 3);
  const int m0i = mb << 8, n0i = nb << 8;

  const int scol = (((tid & 7) ^ ((tid >> 3) & 7)) << 3);  // pre-swz source col

  f32x4 acc[8][4];
  #pragma unroll
  for (int i = 0; i < 8; ++i)
    #pragma unroll
    for (int jj = 0; jj < 4; ++jj) acc[i][jj] = (f32x4){0.f, 0.f, 0.f, 0.f};

  // STG: one 8KB chunk (64 rows x 128B), linear LDS dest, pre-swz source
  auto STG = [&](const unsigned short* gsrc, int baserow, int dstoff, int kt) {
    GLOAD16(gsrc + ((size_t)(baserow + (tid >> 3)) << 9) + (kt << 6) + scol,
            smem + dstoff + (tid << 4));
  };
  auto STGALL = [&](int buf, int kt) {
    STG(Rt, n0i, buf + 32768, kt);        STG(Rt, n0i + 64, buf + 40960, kt);
    STG(Rt, n0i + 128, buf + 49152, kt);  STG(Rt, n0i + 192, buf + 57344, kt);
    STG(Lt, m0i, buf + 0, kt);            STG(Lt, m0i + 64, buf + 8192, kt);
    STG(Lt, m0i + 128, buf + 16384, kt);  STG(Lt, m0i + 192, buf + 24576, kt);
  };

  // prologue: tiles 0 and 1
  STGALL(0, 0);
  STGALL(65536, 1);
  asm volatile("s_waitcnt vmcnt(8)" ::: "memory");  // tile 0 landed
  __builtin_amdgcn_s_barrier();

  #pragma unroll 1
  for (int t = 0; t < 8; ++t) {
    const char* bufp = smem + ((t & 1) << 16);
    #pragma unroll
    for (int kk = 0; kk < 2; ++kk) {
      bf16x8 af[8], bfv[4];
      #pragma unroll
      for (int mi = 0; mi < 8; ++mi) {
        const int row = (wr << 7) + (mi << 4) + mrow;
        af[mi] = *(const bf16x8*)(bufp + (row << 7) +
                                  ((((kk << 2) + g) ^ (row & 7)) << 4));
      }
      #pragma unroll
      for (int ni = 0; ni < 4; ++ni) {
        const int row = (wc << 6) + (ni << 4) + mrow;
        bfv[ni] = *(const bf16x8*)(bufp + 32768 + (row << 7) +
                                   ((((kk << 2) + g) ^ (row & 7)) << 4));
      }
      #pragma unroll
      for (int mi = 0; mi < 8; ++mi)
        #pragma unroll
        for (int ni = 0; ni < 4; ++ni)
          acc[mi][ni] = __builtin_amdgcn_mfma_f32_16x16x32_bf16(
              af[mi], bfv[ni], acc[mi][ni], 0, 0, 0);
    }
    if (t < 6) {
      __builtin_amdgcn_s_barrier();                     // all reads of cbuf done
      STGALL((t & 1) << 16, t + 2);                     // stage t+2 into cbuf
      asm volatile("s_waitcnt vmcnt(8)" ::: "memory");  // t+1 landed
      __builtin_amdgcn_s_barrier();
    } else if (t == 6) {
      asm volatile("s_waitcnt vmcnt(0)" ::: "memory");  // tile 7 landed
      __builtin_amdgcn_s_barrier();
    }
  }
  __syncthreads();

  // scatter op tile -> opvec[p][k2'] bf16, p = bloc*8+dloc, k2' = e*32+c, dual-XOR swz
  #pragma unroll
  for (int mi = 0; mi < 8; ++mi) {
    #pragma unroll
    for (int ni = 0; ni < 4; ++ni) {
      const int p = (((wr << 2) + (mi >> 1)) << 3) | ((wc << 1) + (ni >> 1));
      const int ow_ = ((ni & 1) << 10) + (mrow << 6) + ((mi & 1) << 5) + (g << 3);
      u16x4 pk;
      #pragma unroll
      for (int qq = 0; qq < 4; ++qq) pk[qq] = f2bf(acc[mi][ni][qq]);
      *(u16x4*)(smem + (p << 11) + (ow_ ^ ((p & 7) << 4) ^ (((ow_ >> 7) & 7) << 4))) = pk;
    }
  }
  __syncthreads();

  // prefetch nrm + rcp (hidden under stage2)
  f32x4 invn[4];
  #pragma unroll
  for (int pg = 0; pg < 4; ++pg) {
    const int bb = (mb << 3) + (pg << 1) + (g >> 1);
    const f32x4 nv = *(const f32x4*)(nrm + (bb << 8) + (nb << 3) + ((g & 1) << 2));
    #pragma unroll
    for (int qq = 0; qq < 4; ++qq) invn[pg][qq] = __builtin_amdgcn_rcpf(1e-3f + nv[qq]);
  }

  // stage 2: out2[p][f] = sum_k2' opvec[p][k2'] * Wt[f][k2']; wave owns 16 f x 64 p
  const int f0 = w << 4;
  f32x4 acc2[4];
  #pragma unroll
  for (int i = 0; i < 4; ++i) acc2[i] = (f32x4){0.f, 0.f, 0.f, 0.f};
  const unsigned short* wrow = Wt + (size_t)(f0 + mrow) * 1024;
  #pragma unroll 8
  for (int kk2 = 0; kk2 < 32; ++kk2) {
    const bf16x8 b2 = *(const bf16x8*)(wrow + (kk2 << 5) + (g << 3));
    const int orr = (kk2 << 6) + (g << 4);
    #pragma unroll
    for (int pg = 0; pg < 4; ++pg) {
      const int prow = (pg << 4) + mrow;
      const bf16x8 a2 = *(const bf16x8*)(smem + (prow << 11) +
          (orr ^ ((prow & 7) << 4) ^ (((orr >> 7) & 7) << 4)));
      acc2[pg] = __builtin_amdgcn_mfma_f32_16x16x32_bf16(a2, b2, acc2[pg], 0, 0, 0);
    }
  }

  // epilogue: bias, * (1/(eps+norm)), store
  const float ob_ = outb[f0 + mrow];
  #pragma unroll
  for (int pg = 0; pg < 4; ++pg) {
    #pragma unroll
    for (int qq = 0; qq < 4; ++qq) {
      const int p = (pg << 4) + (g << 2) + qq;
      const int bb = (mb << 3) + (p >> 3);
      const int dd = (nb << 3) + (p & 7);
      out[(size_t)((bb << 8) + dd) * 128 + f0 + mrow] = (acc2[pg][qq] + ob_) * invn[pg][qq];
    }
  }
}

extern "C" void kernel_launch(void* const* d_in, const int* in_sizes, int n_in,
                              void* d_out, int out_size, void* d_ws, size_t ws_size,
                              hipStream_t stream) {
  const float* act = (const float*)d_in[0];
  const float* mask = (const float*)d_in[1];
  const float* lns = (const float*)d_in[2];
  const float* lno = (const float*)d_in[3];
  const float* lw = (const float*)d_in[4];
  const float* lb = (const float*)d_in[5];
  const float* rw = (const float*)d_in[6];
  const float* rbv = (const float*)d_in[7];
  const float* ow = (const float*)d_in[8];
  const float* ob = (const float*)d_in[9];
  float* out = (float*)d_out;
  char* ws = (char*)d_ws;

  unsigned short* Lt = (unsigned short*)(ws);               // 8 MB
  unsigned short* Rt = (unsigned short*)(ws + 8388608);     // 8 MB
  unsigned short* Wt = (unsigned short*)(ws + 16777216);    // 256 KB
  unsigned short* wfragG = (unsigned short*)(ws + 17039360);// 32 KB
  float* nrm = (float*)(ws + 17072128);                     // 256 KB

  hipLaunchKernelGGL(prep_norm_k, dim3(768), dim3(256), 0, stream,
                     lw, rw, ow, mask, Wt, wfragG, nrm);
  hipLaunchKernelGGL(ln_proj, dim3(8, 256), dim3(256), 0, stream,
                     act, mask, lns, lno, lb, rbv, wfragG, Lt, Rt);
  hipLaunchKernelGGL(gemm_fused, dim3(1024), dim3(512), 0, stream,
                     Lt, Rt, Wt, nrm, ob, out);
}